// Round 11
// baseline (133.799 us; speedup 1.0000x reference)
//
#include <hip/hip_runtime.h>
#include <cstddef>

#define LL 4096
#define BB 2
#define DD 256
#define NEL ((size_t)BB * LL * DD) /* 2097152 */

typedef __bf16 bf16x8 __attribute__((ext_vector_type(8)));
typedef float f32x4 __attribute__((ext_vector_type(4)));
typedef unsigned short u16;

__device__ __forceinline__ float4 ld4(const float* p) { return *reinterpret_cast<const float4*>(p); }
__device__ __forceinline__ void st4(float* p, const float4 v) { *reinterpret_cast<float4*>(p) = v; }
__device__ __forceinline__ float softplusf(float x) { return fmaxf(x, 0.f) + log1pf(expf(-fabsf(x))); }
__device__ __forceinline__ u16 f2b(float f) {
    union { float f; unsigned u; } v; v.f = f;
    unsigned u = v.u;
    return (u16)((u + 0x7fffu + ((u >> 16) & 1u)) >> 16);
}

// load 16 consecutive floats at p; if !fwd, reverse into scan order (x/z only)
__device__ __forceinline__ void load16(const float* __restrict__ p, int fwd, float* dst) {
    if (fwd) {
#pragma unroll
        for (int k = 0; k < 4; ++k) {
            float4 v = ld4(p + 4 * k);
            dst[4 * k] = v.x; dst[4 * k + 1] = v.y; dst[4 * k + 2] = v.z; dst[4 * k + 3] = v.w;
        }
    } else {
#pragma unroll
        for (int k = 0; k < 4; ++k) {
            float4 v = ld4(p + 4 * k);
            dst[15 - 4 * k] = v.x; dst[14 - 4 * k] = v.y; dst[13 - 4 * k] = v.z; dst[12 - 4 * k] = v.w;
        }
    }
}

// scan-ordered chunk layout [s4(4)][tt(256)][j(4)]; 512-thread variant:
// thread t owns positions [8t, 8t+8) = s4-chunks {2(t&1), 2(t&1)+1} of tt=t>>1.
__device__ __forceinline__ void load8s(const float* __restrict__ row, int t, float* dst) {
    const int tt = t >> 1;
    const int s4b = (t & 1) * 2;
#pragma unroll
    for (int q = 0; q < 2; ++q) {
        float4 v = ld4(row + (s4b + q) * 1024 + tt * 4);
        dst[4 * q] = v.x; dst[4 * q + 1] = v.y; dst[4 * q + 2] = v.z; dst[4 * q + 3] = v.w;
    }
}

// ---------------- bf16 weight panel layout (u16 offsets from wsH) ----------------
//  Wxz  @ 0      : 512 n x 256 k  (= in_proj_W, native row-major)
//  Wcw  @ 131072 : 256 n x 512 k  (= cw_W)
//  Wdtf @ 262144 : 256 n x 256 k  (composed dt fwd)
//  Wdtb @ 327680 : 256 n x 256 k  (composed dt bwd)
//  Wbc  @ 393216 : 64 n x 256 k   (rows 0-31 fwd B/C comps, 32-63 bwd)
//  Wout @ 409600 : 256 n x 256 k  (= out_proj_W)

__global__ __launch_bounds__(256) void prep_q(
    const float* __restrict__ xpf, const float* __restrict__ xpb,
    const float* __restrict__ extW, float* __restrict__ Q, u16* __restrict__ wsH)
{
    const int r = blockIdx.x % 48;
    const int dir = blockIdx.x / 48;
    const int k = threadIdx.x;
    const float* xp = dir ? xpb : xpf;    // (48,256)
    float s = 0.f;
    for (int n = 0; n < 256; ++n) s = fmaf(xp[r * 256 + n], extW[n * 256 + k], s);
    if (r < 16) Q[(dir * 16 + r) * 256 + k] = s;
    else        wsH[393216 + ((dir ? 32 : 0) + (r - 16)) * 256 + k] = f2b(s);
}

__global__ __launch_bounds__(256) void prep_w(
    const float* __restrict__ inW, const float* __restrict__ cwW,
    const float* __restrict__ outW, const float* __restrict__ dtfW,
    const float* __restrict__ dtbW, const float* __restrict__ Q,
    u16* __restrict__ wsH)
{
    const int idx = blockIdx.x * 256 + threadIdx.x;
    if (idx < 131072) {
        wsH[idx] = f2b(inW[idx]);
    } else if (idx < 262144) {
        wsH[idx] = f2b(cwW[idx - 131072]);
    } else if (idx < 393216) {
        const int i = idx - 262144;
        const int dir = i >> 16;
        const int j = i & 65535;
        const int n = j >> 8, k = j & 255;
        const float* dtW = dir ? dtbW : dtfW;      // (256,16)
        const float* Qd = Q + dir * 4096;
        float s = 0.f;
#pragma unroll
        for (int r = 0; r < 16; ++r) s = fmaf(dtW[n * 16 + r], Qd[r * 256 + k], s);
        wsH[idx] = f2b(s);
    } else if (idx >= 409600 && idx < 475136) {
        wsH[idx] = f2b(outW[idx - 409600]);
    }
}

// ---------------- row LayerNorm (256 cols), one wave per row; fp32 + bf16 out ----------------
__global__ __launch_bounds__(64) void ln_rows(
    const float* __restrict__ in, float* __restrict__ outf, u16* __restrict__ outh,
    const float* __restrict__ g, const float* __restrict__ bb)
{
    const int row = blockIdx.x;
    const int t = threadIdx.x;
    const size_t off = (size_t)row * 256 + t * 4;
    float4 v = ld4(&in[off]);
    float s = v.x + v.y + v.z + v.w;
    float s2 = v.x * v.x + v.y * v.y + v.z * v.z + v.w * v.w;
#pragma unroll
    for (int dl = 1; dl < 64; dl <<= 1) { s += __shfl_xor(s, dl); s2 += __shfl_xor(s2, dl); }
    const float m = s * (1.f / 256.f);
    const float var = s2 * (1.f / 256.f) - m * m;
    const float rstd = rsqrtf(var + 1e-5f);
    const float4 gv = ld4(&g[t * 4]);
    const float4 bv = ld4(&bb[t * 4]);
    float4 r;
    r.x = (v.x - m) * rstd * gv.x + bv.x;
    r.y = (v.y - m) * rstd * gv.y + bv.y;
    r.z = (v.z - m) * rstd * gv.z + bv.z;
    r.w = (v.w - m) * rstd * gv.w + bv.w;
    if (outf) st4(&outf[off], r);
    ushort4 h; h.x = f2b(r.x); h.y = f2b(r.y); h.z = f2b(r.z); h.w = f2b(r.w);
    *reinterpret_cast<ushort4*>(&outh[off]) = h;
}

// ---------------- fused MFMA GEMM with LDS-staged B panel ----------------
// grid (64 m-tiles of 128, 21 by). block 256 = 4 waves; tile 128(M)x64(N);
// wave w owns rows [w*32, w*32+32) as two 16-row groups.
// by: 0-3 x | 4-7 z | 8-11 w(sigmoid,K=512 two halves) | 12-15 dtf | 16-19 dtb | 20 bc
// B panel: 64 n x 256 k bf16 in LDS = 64 rows x 32 chunks(8 u16);
// XOR-swizzled (byte ^= (row&7)<<4) -> conflict-free ds_read_b128 (G4).
// dt and bc outputs are written in chunk-transposed SCAN-ORDER layout
// [row][s4][tt][j] (bwd pre-reversed) so the scan loads coalesce.
__global__ __launch_bounds__(256) void gemm_mfma(
    const u16* __restrict__ x0h, const u16* __restrict__ x1h, const u16* __restrict__ wsH,
    const float* __restrict__ cwb, const float* __restrict__ dtfb, const float* __restrict__ dtbb,
    float* __restrict__ xT, float* __restrict__ zT, float* __restrict__ wbuf,
    float* __restrict__ dtfT, float* __restrict__ dtbT,
    float* __restrict__ bcfT, float* __restrict__ bcbT)
{
    __shared__ __align__(16) u16 Blds[64 * 256];   // 32 KB
    const int t = threadIdx.x;
    const int lane = t & 63;
    const int wid = t >> 6;
    const int col = lane & 15;
    const int kq = lane >> 4;
    const int m0 = blockIdx.x * 128;
    const int by = blockIdx.y;

    int seg, nbase, ldk, nhalf; const u16* W;
    if (by < 4)       { seg = 0; W = wsH + (size_t)(by * 64) * 256;                 ldk = 256; nhalf = 1; nbase = by * 64; }
    else if (by < 8)  { seg = 1; W = wsH + (size_t)(by * 64) * 256;                 ldk = 256; nhalf = 1; nbase = (by - 4) * 64; }
    else if (by < 12) { seg = 2; W = wsH + 131072 + (size_t)((by - 8) * 64) * 512;  ldk = 512; nhalf = 2; nbase = (by - 8) * 64; }
    else if (by < 16) { seg = 3; W = wsH + 262144 + (size_t)((by - 12) * 64) * 256; ldk = 256; nhalf = 1; nbase = (by - 12) * 64; }
    else if (by < 20) { seg = 4; W = wsH + 327680 + (size_t)((by - 16) * 64) * 256; ldk = 256; nhalf = 1; nbase = (by - 16) * 64; }
    else              { seg = 5; W = wsH + 393216;                                  ldk = 256; nhalf = 1; nbase = 0; }

    const u16* A0 = (seg >= 3) ? x1h : x0h;
    const int arow = m0 + wid * 32 + col;

    f32x4 acc[2][4] = {};
    for (int half = 0; half < nhalf; ++half) {
        if (half) __syncthreads();
        // stage B panel: 2048 chunks = 64 rows x 32 chunks; 8 chunks/thread
#pragma unroll
        for (int it = 0; it < 8; ++it) {
            const int c = it * 256 + t;
            const int row = c >> 5, kc = c & 31;
            const bf16x8 v = *reinterpret_cast<const bf16x8*>(W + (size_t)row * ldk + half * 256 + kc * 8);
            const unsigned byt = ((unsigned)(row * 512 + kc * 16)) ^ (((unsigned)row & 7u) << 4);
            *reinterpret_cast<bf16x8*>(reinterpret_cast<char*>(Blds) + byt) = v;
        }
        __syncthreads();
        const u16* Ap = (seg == 2 && half) ? x1h : A0;
        const u16* Abase = Ap + (size_t)arow * 256;
        for (int k0 = 0; k0 < 256; k0 += 32) {
            const int kk = k0 + kq * 8;
            const bf16x8 a0 = *reinterpret_cast<const bf16x8*>(Abase + kk);
            const bf16x8 a1 = *reinterpret_cast<const bf16x8*>(Abase + 16 * 256 + kk);
#pragma unroll
            for (int nf = 0; nf < 4; ++nf) {
                const int n = nf * 16 + col;
                const unsigned byt = ((unsigned)(n * 512 + k0 * 2 + kq * 16)) ^ (((unsigned)n & 7u) << 4);
                const bf16x8 bfr = *reinterpret_cast<const bf16x8*>(reinterpret_cast<const char*>(Blds) + byt);
                acc[0][nf] = __builtin_amdgcn_mfma_f32_16x16x32_bf16(a0, bfr, acc[0][nf], 0, 0, 0);
                acc[1][nf] = __builtin_amdgcn_mfma_f32_16x16x32_bf16(a1, bfr, acc[1][nf], 0, 0, 0);
            }
        }
    }

    const int bb2 = m0 >> 12;
    const int l0 = m0 & (LL - 1);

    if (seg == 0 || seg == 1) {
        float* dst = (seg == 0) ? xT : zT;
#pragma unroll
        for (int rg = 0; rg < 2; ++rg) {
            const int mrow = wid * 32 + rg * 16 + kq * 4;
#pragma unroll
            for (int nf = 0; nf < 4; ++nf) {
                const int d = nbase + nf * 16 + col;
                *reinterpret_cast<f32x4*>(&dst[((size_t)bb2 * DD + d) * LL + l0 + mrow]) = acc[rg][nf];
            }
        }
    } else if (seg == 2) {
#pragma unroll
        for (int rg = 0; rg < 2; ++rg) {
            const int mrow = wid * 32 + rg * 16 + kq * 4;
#pragma unroll
            for (int nf = 0; nf < 4; ++nf) {
                const int n = nbase + nf * 16 + col;
                const float bv = cwb[n];
#pragma unroll
                for (int r = 0; r < 4; ++r)
                    wbuf[(size_t)(m0 + mrow + r) * 256 + n] = 1.f / (1.f + expf(-(acc[rg][nf][r] + bv)));
            }
        }
    } else if (seg == 3 || seg == 4) {
        const float* bias = (seg == 3) ? dtfb : dtbb;
        float* dst = (seg == 3) ? dtfT : dtbT;
#pragma unroll
        for (int rg = 0; rg < 2; ++rg) {
            const int tt = (l0 >> 4) + wid * 2 + rg;
#pragma unroll
            for (int nf = 0; nf < 4; ++nf) {
                const int d = nbase + nf * 16 + col;
                const float bv = bias[d];
                f32x4 o;
#pragma unroll
                for (int r = 0; r < 4; ++r) o[r] = softplusf(acc[rg][nf][r] + bv);
                const size_t rowb = ((size_t)bb2 * DD + d) * LL;
                if (seg == 3) {
                    *reinterpret_cast<f32x4*>(&dst[rowb + kq * 1024 + tt * 4]) = o;
                } else {
                    f32x4 orv = { o[3], o[2], o[1], o[0] };
                    *reinterpret_cast<f32x4*>(&dst[rowb + (3 - kq) * 1024 + (255 - tt) * 4]) = orv;
                }
            }
        }
    } else {
#pragma unroll
        for (int rg = 0; rg < 2; ++rg) {
            const int tt = (l0 >> 4) + wid * 2 + rg;
#pragma unroll
            for (int nf = 0; nf < 4; ++nf) {
                const int n = nf * 16 + col;
                const int comp = n & 31;
                if (n < 32) {
                    const size_t rowb = ((size_t)bb2 * 32 + comp) * LL;
                    *reinterpret_cast<f32x4*>(&bcfT[rowb + kq * 1024 + tt * 4]) = acc[rg][nf];
                } else {
                    const f32x4 a = acc[rg][nf];
                    f32x4 arv = { a[3], a[2], a[1], a[0] };
                    const size_t rowb = ((size_t)bb2 * 32 + comp) * LL;
                    *reinterpret_cast<f32x4*>(&bcbT[rowb + (3 - kq) * 1024 + (255 - tt) * 4]) = arv;
                }
            }
        }
    }
}

// ---------------- out-proj MFMA GEMM (row-major out), LDS-staged B ----------------
__global__ __launch_bounds__(256) void gemm_out_mfma(
    const u16* __restrict__ ynh, const u16* __restrict__ wsH, float* __restrict__ out)
{
    __shared__ __align__(16) u16 Blds[64 * 256];
    const int t = threadIdx.x;
    const int lane = t & 63;
    const int wid = t >> 6;
    const int col = lane & 15;
    const int kq = lane >> 4;
    const int m0 = blockIdx.x * 128;
    const int n0 = blockIdx.y * 64;
    const u16* W = wsH + 409600 + (size_t)n0 * 256;
    const int arow = m0 + wid * 32 + col;

#pragma unroll
    for (int it = 0; it < 8; ++it) {
        const int c = it * 256 + t;
        const int row = c >> 5, kc = c & 31;
        const bf16x8 v = *reinterpret_cast<const bf16x8*>(W + (size_t)row * 256 + kc * 8);
        const unsigned byt = ((unsigned)(row * 512 + kc * 16)) ^ (((unsigned)row & 7u) << 4);
        *reinterpret_cast<bf16x8*>(reinterpret_cast<char*>(Blds) + byt) = v;
    }
    __syncthreads();

    f32x4 acc[2][4] = {};
    const u16* Abase = ynh + (size_t)arow * 256;
    for (int k0 = 0; k0 < 256; k0 += 32) {
        const int kk = k0 + kq * 8;
        const bf16x8 a0 = *reinterpret_cast<const bf16x8*>(Abase + kk);
        const bf16x8 a1 = *reinterpret_cast<const bf16x8*>(Abase + 16 * 256 + kk);
#pragma unroll
        for (int nf = 0; nf < 4; ++nf) {
            const int n = nf * 16 + col;
            const unsigned byt = ((unsigned)(n * 512 + k0 * 2 + kq * 16)) ^ (((unsigned)n & 7u) << 4);
            const bf16x8 bfr = *reinterpret_cast<const bf16x8*>(reinterpret_cast<const char*>(Blds) + byt);
            acc[0][nf] = __builtin_amdgcn_mfma_f32_16x16x32_bf16(a0, bfr, acc[0][nf], 0, 0, 0);
            acc[1][nf] = __builtin_amdgcn_mfma_f32_16x16x32_bf16(a1, bfr, acc[1][nf], 0, 0, 0);
        }
    }
#pragma unroll
    for (int rg = 0; rg < 2; ++rg) {
        const int mrow = wid * 32 + rg * 16 + kq * 4;
#pragma unroll
        for (int nf = 0; nf < 4; ++nf) {
            const int n = n0 + nf * 16 + col;
#pragma unroll
            for (int r = 0; r < 4; ++r)
                out[(size_t)(m0 + mrow + r) * 256 + n] = acc[rg][nf][r];
        }
    }
}

// ---------------- selective scan (512 threads, 8 positions/thread) ----------------
// grid (256 d, 2 b, 2 dir), block 512 = 8 waves. Thread t owns positions
// [8t, 8t+8). Halved serial chains + 2x waves vs the 256-thread version.
// dt/B/C in scan-ordered chunk-transposed layout. n-loop MUST NOT unroll
// (spill lesson rounds 2-4).
__global__ __launch_bounds__(512) void scan_kernel(
    const float* __restrict__ xT, const float* __restrict__ zT,
    const float* __restrict__ dtfT, const float* __restrict__ dtbT,
    const float* __restrict__ bcfT, const float* __restrict__ bcbT,
    const float* __restrict__ cfW, const float* __restrict__ cfB,
    const float* __restrict__ cbW, const float* __restrict__ cbB,
    const float* __restrict__ AlF, const float* __restrict__ AlB,
    const float* __restrict__ DF, const float* __restrict__ DB,
    float* __restrict__ yF, float* __restrict__ yB)
{
    const int d = blockIdx.x;
    const int b = blockIdx.y;
    const int dir = blockIdx.z;
    const int t = threadIdx.x;
    const int lane = t & 63;
    const int wv = t >> 6;
    const int fwd = (dir == 0);
    const float* dtT = fwd ? dtfT : dtbT;
    const float* bcT = fwd ? bcfT : bcbT;
    const float* cW  = fwd ? cfW  : cbW;
    const float* cBv = fwd ? cfB  : cbB;
    const float* Al  = fwd ? AlF  : AlB;
    const float* Dp  = fwd ? DF   : DB;
    float* yout = fwd ? yF : yB;

    const int p0 = t * 8;
    const size_t xbase = ((size_t)b * DD + d) * LL;
    const int ls = LL - 8 - p0;

    const float Dd = Dp[d];
    const float c0 = cW[d * 4 + 0], c1 = cW[d * 4 + 1], c2 = cW[d * 4 + 2], c3 = cW[d * 4 + 3];
    const float cbias = cBv[d];

    // x window xq[i] = xseq(p0 - 3 + i), i = 0..10
    float xq[11];
    if (fwd) {
#pragma unroll
        for (int k = 0; k < 2; ++k) {
            float4 v = ld4(&xT[xbase + p0 + 4 * k]);
            xq[3 + 4 * k] = v.x; xq[4 + 4 * k] = v.y; xq[5 + 4 * k] = v.z; xq[6 + 4 * k] = v.w;
        }
        xq[2] = (p0 >= 1) ? xT[xbase + p0 - 1] : 0.f;
        xq[1] = (p0 >= 2) ? xT[xbase + p0 - 2] : 0.f;
        xq[0] = (p0 >= 3) ? xT[xbase + p0 - 3] : 0.f;
    } else {
#pragma unroll
        for (int k = 0; k < 2; ++k) {
            float4 v = ld4(&xT[xbase + ls + 4 * k]);
            xq[10 - 4 * k] = v.x; xq[9 - 4 * k] = v.y; xq[8 - 4 * k] = v.z; xq[7 - 4 * k] = v.w;
        }
        xq[2] = (p0 >= 1) ? xT[xbase + LL - p0] : 0.f;
        xq[1] = (p0 >= 2) ? xT[xbase + LL + 1 - p0] : 0.f;
        xq[0] = (p0 >= 3) ? xT[xbase + LL + 2 - p0] : 0.f;
    }

    float dt[8];
    load8s(dtT + xbase, t, dt);

    float dtxs[8], yacc[8];
#pragma unroll
    for (int s = 0; s < 8; ++s) {
        float c = fmaf(xq[s], c0, fmaf(xq[s + 1], c1, fmaf(xq[s + 2], c2, fmaf(xq[s + 3], c3, cbias))));
        const float xv = c / (1.f + expf(-c));
        dtxs[s] = dt[s] * xv;
        yacc[s] = Dd * xv;
    }

    const float* bcb0 = bcT + (size_t)b * 32 * LL;

    __shared__ float wPs[2][8];
    __shared__ float wSs[2][8];

#pragma unroll 1
    for (int n = 0; n < 16; ++n) {
        const float a2 = -expf(Al[d * 16 + n]) * 1.4426950408889634f;
        float Bn[8];
        load8s(bcb0 + (size_t)n * LL, t, Bn);
        float pw[8], hl[8];
        float Pl = 1.f, Sl = 0.f;
#pragma unroll
        for (int s = 0; s < 8; ++s) {
            const float w = exp2f(dt[s] * a2);
            Sl = fmaf(w, Sl, dtxs[s] * Bn[s]);
            Pl *= w;
            pw[s] = Pl; hl[s] = Sl;
        }
        float Cn[8];
        load8s(bcb0 + (size_t)(16 + n) * LL, t, Cn);
        // wave-inclusive scan of (Pl,Sl)
#pragma unroll
        for (int dl = 1; dl < 64; dl <<= 1) {
            const float Pp = __shfl_up(Pl, dl);
            const float Sp = __shfl_up(Sl, dl);
            if (lane >= dl) { Sl = fmaf(Pl, Sp, Sl); Pl *= Pp; }
        }
        const int buf = n & 1;
        if (lane == 63) { wPs[buf][wv] = Pl; wSs[buf][wv] = Sl; }
        __syncthreads();
        float WSv = 0.f;
#pragma unroll
        for (int w2 = 0; w2 < 7; ++w2)
            if (w2 < wv) WSv = fmaf(wPs[buf][w2], WSv, wSs[buf][w2]);
        const float Pex = __shfl_up(Pl, 1);
        const float Sex = __shfl_up(Sl, 1);
        const float hin = lane ? fmaf(Pex, WSv, Sex) : WSv;
#pragma unroll
        for (int s = 0; s < 8; ++s)
            yacc[s] = fmaf(fmaf(pw[s], hin, hl[s]), Cn[s], yacc[s]);
    }

    float zq[8];
    if (fwd) {
#pragma unroll
        for (int k = 0; k < 2; ++k) {
            float4 v = ld4(&zT[xbase + p0 + 4 * k]);
            zq[4 * k] = v.x; zq[4 * k + 1] = v.y; zq[4 * k + 2] = v.z; zq[4 * k + 3] = v.w;
        }
    } else {
#pragma unroll
        for (int k = 0; k < 2; ++k) {
            float4 v = ld4(&zT[xbase + ls + 4 * k]);
            zq[7 - 4 * k] = v.x; zq[6 - 4 * k] = v.y; zq[5 - 4 * k] = v.z; zq[4 - 4 * k] = v.w;
        }
    }
    float yv[8];
#pragma unroll
    for (int s = 0; s < 8; ++s) {
        const float zz = zq[s];
        yv[s] = yacc[s] * zz / (1.f + expf(-zz));
    }

    if (fwd) {
#pragma unroll
        for (int k = 0; k < 2; ++k)
            st4(&yout[xbase + p0 + 4 * k], make_float4(yv[4 * k], yv[4 * k + 1], yv[4 * k + 2], yv[4 * k + 3]));
    } else {
#pragma unroll
        for (int k = 0; k < 2; ++k)
            st4(&yout[xbase + ls + 4 * k], make_float4(yv[7 - 4 * k], yv[6 - 4 * k], yv[5 - 4 * k], yv[4 - 4 * k]));
    }
}

// ---------------- (yf+yb)/2 + transpose + outnorm LN fused, bf16 out ----------------
// grid (128 l-tiles of 32, 2 b), block 256
__global__ __launch_bounds__(256) void comb_ln(
    const float* __restrict__ yF, const float* __restrict__ yB,
    const float* __restrict__ g, const float* __restrict__ bb,
    u16* __restrict__ out)
{
    __shared__ float tile[256][33];
    __shared__ float rs[8][32];
    __shared__ float rs2[8][32];
    const int b = blockIdx.y;
    const int l0 = blockIdx.x * 32;
    const int t = threadIdx.x;
    {
        const size_t base = ((size_t)b * DD + t) * LL + l0;
#pragma unroll
        for (int k = 0; k < 8; ++k) {
            float4 f = ld4(&yF[base + 4 * k]);
            float4 bv = ld4(&yB[base + 4 * k]);
            tile[t][4 * k + 0] = (f.x + bv.x) * 0.5f;
            tile[t][4 * k + 1] = (f.y + bv.y) * 0.5f;
            tile[t][4 * k + 2] = (f.z + bv.z) * 0.5f;
            tile[t][4 * k + 3] = (f.w + bv.w) * 0.5f;
        }
    }
    __syncthreads();
    const int l = t & 31;
    const int grp = t >> 5;
    float s = 0.f, s2 = 0.f;
#pragma unroll
    for (int i = 0; i < 32; ++i) {
        const float v = tile[grp * 32 + i][l];
        s += v; s2 = fmaf(v, v, s2);
    }
    rs[grp][l] = s; rs2[grp][l] = s2;
    __syncthreads();
    float st = 0.f, st2 = 0.f;
#pragma unroll
    for (int gq = 0; gq < 8; ++gq) { st += rs[gq][l]; st2 += rs2[gq][l]; }
    const float m = st * (1.f / 256.f);
    const float var = st2 * (1.f / 256.f) - m * m;
    const float rstd = rsqrtf(var + 1e-5f);
    const size_t obase = ((size_t)b * LL + l0 + l) * 256 + grp * 32;
#pragma unroll
    for (int k = 0; k < 8; ++k) {
        const float4 gv = ld4(&g[grp * 32 + 4 * k]);
        const float4 bv2 = ld4(&bb[grp * 32 + 4 * k]);
        ushort4 h;
        h.x = f2b((tile[grp * 32 + 4 * k + 0][l] - m) * rstd * gv.x + bv2.x);
        h.y = f2b((tile[grp * 32 + 4 * k + 1][l] - m) * rstd * gv.y + bv2.y);
        h.z = f2b((tile[grp * 32 + 4 * k + 2][l] - m) * rstd * gv.z + bv2.z);
        h.w = f2b((tile[grp * 32 + 4 * k + 3][l] - m) * rstd * gv.w + bv2.w);
        *reinterpret_cast<ushort4*>(&out[obase + 4 * k]) = h;
    }
}

// ---------------- post-LN + gated blend + skip ----------------
__global__ __launch_bounds__(64) void final_kernel(
    const float* __restrict__ o, const float* __restrict__ w,
    const float* __restrict__ x0n, const float* __restrict__ in0,
    const float* __restrict__ pg, const float* __restrict__ pb,
    float* __restrict__ outp)
{
    const int row = blockIdx.x;
    const int t = threadIdx.x;
    const size_t off = (size_t)row * 256 + t * 4;
    float4 v = ld4(&o[off]);
    float s = v.x + v.y + v.z + v.w;
    float s2 = v.x * v.x + v.y * v.y + v.z * v.z + v.w * v.w;
#pragma unroll
    for (int dl = 1; dl < 64; dl <<= 1) { s += __shfl_xor(s, dl); s2 += __shfl_xor(s2, dl); }
    const float m = s * (1.f / 256.f);
    const float var = s2 * (1.f / 256.f) - m * m;
    const float rstd = rsqrtf(var + 1e-5f);
    const float4 gv = ld4(&pg[t * 4]);
    const float4 bv = ld4(&pb[t * 4]);
    const float4 wv = ld4(&w[off]);
    const float4 xv = ld4(&x0n[off]);
    const float4 iv = ld4(&in0[off]);
    float4 r;
    r.x = ((v.x - m) * rstd * gv.x + bv.x) * wv.x + xv.x * (1.f - wv.x) + iv.x;
    r.y = ((v.y - m) * rstd * gv.y + bv.y) * wv.y + xv.y * (1.f - wv.y) + iv.y;
    r.z = ((v.z - m) * rstd * gv.z + bv.z) * wv.z + xv.z * (1.f - wv.z) + iv.z;
    r.w = ((v.w - m) * rstd * gv.w + bv.w) * wv.w + xv.w * (1.f - wv.w) + iv.w;
    st4(&outp[off], r);
}

extern "C" void kernel_launch(void* const* d_in, const int* in_sizes, int n_in,
                              void* d_out, int out_size, void* d_ws, size_t ws_size,
                              hipStream_t stream) {
    (void)in_sizes; (void)n_in; (void)out_size; (void)ws_size;
    const float* in0      = (const float*)d_in[0];
    const float* in1      = (const float*)d_in[1];
    const float* norm0_g  = (const float*)d_in[2];
    const float* norm0_b  = (const float*)d_in[3];
    const float* norm1_g  = (const float*)d_in[4];
    const float* norm1_b  = (const float*)d_in[5];
    const float* cw_W     = (const float*)d_in[6];
    const float* cw_b     = (const float*)d_in[7];
    const float* in_proj_W    = (const float*)d_in[8];
    const float* extra_proj_W = (const float*)d_in[9];
    const float* convf_W  = (const float*)d_in[10];
    const float* convf_b  = (const float*)d_in[11];
    const float* xprojf_W = (const float*)d_in[12];
    const float* dtf_W    = (const float*)d_in[13];
    const float* dtf_b    = (const float*)d_in[14];
    const float* A_log_f  = (const float*)d_in[15];
    const float* D_f      = (const float*)d_in[16];
    const float* convb_W  = (const float*)d_in[17];
    const float* convb_b  = (const float*)d_in[18];
    const float* xprojb_W = (const float*)d_in[19];
    const float* dtb_W    = (const float*)d_in[20];
    const float* dtb_b    = (const float*)d_in[21];
    const float* A_log_b  = (const float*)d_in[22];
    const float* D_b      = (const float*)d_in[23];
    const float* outnorm_g = (const float*)d_in[24];
    const float* outnorm_b = (const float*)d_in[25];
    const float* out_proj_W = (const float*)d_in[26];
    const float* post_g   = (const float*)d_in[27];
    const float* post_b   = (const float*)d_in[28];

    float* ws = (float*)d_ws;
    float* x0n   = ws;                  // fp32, live to end
    float* xT    = ws + NEL;            // dead after scan
    float* zT    = ws + 2 * NEL;        // dead after scan
    float* dtfT  = ws + 3 * NEL;        // dead after scan -> ynorm (bf16)
    float* dtbT  = ws + 4 * NEL;        // dead after scan -> obuf
    float* wbuf  = ws + 5 * NEL;
    float* yF    = ws + 6 * NEL;        // overlays x0h/x1h (dead after gemm_mfma)
    float* yB    = ws + 7 * NEL;
    float* bcfT  = ws + 8 * NEL;                     // 262144 floats
    float* bcbT  = bcfT + (size_t)BB * 32 * LL;      // 262144 floats
    u16*   wsH   = (u16*)(bcbT + (size_t)BB * 32 * LL);  // 475136 u16
    float* Qtmp  = (float*)(wsH + 475136);               // 8192 floats

    u16* x0h = (u16*)yF;                // 2M u16 = first half of yF region
    u16* x1h = x0h + NEL;               // 2M u16 = second half of yF region
    u16* ynormh = (u16*)dtfT;
    float* obuf = dtbT;

    prep_q<<<96, 256, 0, stream>>>(xprojf_W, xprojb_W, extra_proj_W, Qtmp, wsH);
    prep_w<<<1856, 256, 0, stream>>>(in_proj_W, cw_W, out_proj_W, dtf_W, dtb_W, Qtmp, wsH);
    ln_rows<<<BB * LL, 64, 0, stream>>>(in0, x0n, x0h, norm0_g, norm0_b);
    ln_rows<<<BB * LL, 64, 0, stream>>>(in1, nullptr, x1h, norm1_g, norm1_b);
    gemm_mfma<<<dim3(64, 21, 1), 256, 0, stream>>>(x0h, x1h, wsH, cw_b, dtf_b, dtb_b,
                                                   xT, zT, wbuf, dtfT, dtbT, bcfT, bcbT);
    scan_kernel<<<dim3(256, 2, 2), 512, 0, stream>>>(xT, zT, dtfT, dtbT, bcfT, bcbT,
                                                     convf_W, convf_b, convb_W, convb_b,
                                                     A_log_f, A_log_b, D_f, D_b,
                                                     yF, yB);
    comb_ln<<<dim3(128, 2, 1), 256, 0, stream>>>(yF, yB, outnorm_g, outnorm_b, ynormh);
    gemm_out_mfma<<<dim3(64, 4, 1), 256, 0, stream>>>(ynormh, wsH, obuf);
    final_kernel<<<BB * LL, 64, 0, stream>>>(obuf, wbuf, x0n, in0, post_g, post_b, (float*)d_out);
}

// Round 12
// 118.676 us; speedup vs baseline: 1.1274x; 1.1274x over previous
//
#include <hip/hip_runtime.h>
#include <cstddef>

#define LL 4096
#define BB 2
#define DD 256
#define NEL ((size_t)BB * LL * DD) /* 2097152 */

typedef __bf16 bf16x8 __attribute__((ext_vector_type(8)));
typedef float f32x4 __attribute__((ext_vector_type(4)));
typedef unsigned short u16;

__device__ __forceinline__ float4 ld4(const float* p) { return *reinterpret_cast<const float4*>(p); }
__device__ __forceinline__ void st4(float* p, const float4 v) { *reinterpret_cast<float4*>(p) = v; }
__device__ __forceinline__ float softplusf(float x) { return fmaxf(x, 0.f) + log1pf(expf(-fabsf(x))); }
__device__ __forceinline__ u16 f2b(float f) {
    union { float f; unsigned u; } v; v.f = f;
    unsigned u = v.u;
    return (u16)((u + 0x7fffu + ((u >> 16) & 1u)) >> 16);
}
__device__ __forceinline__ float b2f(unsigned bits16) {
    union { unsigned u; float f; } v; v.u = bits16 << 16; return v.f;
}

// load 16 contiguous bf16 at p; if !fwd, reverse into scan order
__device__ __forceinline__ void load16h(const u16* __restrict__ p, int fwd, float* dst) {
    const uint4 a = *reinterpret_cast<const uint4*>(p);
    const uint4 c = *reinterpret_cast<const uint4*>(p + 8);
    const unsigned* au = reinterpret_cast<const unsigned*>(&a);
    const unsigned* cu = reinterpret_cast<const unsigned*>(&c);
    float tmp[16];
#pragma unroll
    for (int j = 0; j < 4; ++j) {
        tmp[2 * j]     = b2f(au[j] & 0xffffu);
        tmp[2 * j + 1] = b2f(au[j] >> 16);
        tmp[8 + 2 * j]     = b2f(cu[j] & 0xffffu);
        tmp[8 + 2 * j + 1] = b2f(cu[j] >> 16);
    }
    if (fwd) {
#pragma unroll
        for (int s = 0; s < 16; ++s) dst[s] = tmp[s];
    } else {
#pragma unroll
        for (int s = 0; s < 16; ++s) dst[s] = tmp[15 - s];
    }
}

// coalesced scan-ordered chunk load: row layout [s4(4)][tt(256)][j(4)]
__device__ __forceinline__ void load16s(const float* __restrict__ row, int t, float* dst) {
#pragma unroll
    for (int s4 = 0; s4 < 4; ++s4) {
        float4 v = ld4(row + s4 * 1024 + t * 4);
        dst[4 * s4] = v.x; dst[4 * s4 + 1] = v.y; dst[4 * s4 + 2] = v.z; dst[4 * s4 + 3] = v.w;
    }
}

// ---------------- bf16 weight panel layout (u16 offsets from wsH) ----------------
//  Wxz  @ 0      : 512 n x 256 k  (= in_proj_W, native row-major)
//  Wcw  @ 131072 : 256 n x 512 k  (= cw_W)
//  Wdtf @ 262144 : 256 n x 256 k  (composed dt fwd)
//  Wdtb @ 327680 : 256 n x 256 k  (composed dt bwd)
//  Wbc  @ 393216 : 64 n x 256 k   (rows 0-31 fwd B/C comps, 32-63 bwd)
//  Wout @ 409600 : 256 n x 256 k  (= out_proj_W)

__global__ __launch_bounds__(256) void prep_q(
    const float* __restrict__ xpf, const float* __restrict__ xpb,
    const float* __restrict__ extW, float* __restrict__ Q, u16* __restrict__ wsH)
{
    const int r = blockIdx.x % 48;
    const int dir = blockIdx.x / 48;
    const int k = threadIdx.x;
    const float* xp = dir ? xpb : xpf;    // (48,256)
    float s = 0.f;
    for (int n = 0; n < 256; ++n) s = fmaf(xp[r * 256 + n], extW[n * 256 + k], s);
    if (r < 16) Q[(dir * 16 + r) * 256 + k] = s;
    else        wsH[393216 + ((dir ? 32 : 0) + (r - 16)) * 256 + k] = f2b(s);
}

__global__ __launch_bounds__(256) void prep_w(
    const float* __restrict__ inW, const float* __restrict__ cwW,
    const float* __restrict__ outW, const float* __restrict__ dtfW,
    const float* __restrict__ dtbW, const float* __restrict__ Q,
    u16* __restrict__ wsH)
{
    const int idx = blockIdx.x * 256 + threadIdx.x;
    if (idx < 131072) {
        wsH[idx] = f2b(inW[idx]);
    } else if (idx < 262144) {
        wsH[idx] = f2b(cwW[idx - 131072]);
    } else if (idx < 393216) {
        const int i = idx - 262144;
        const int dir = i >> 16;
        const int j = i & 65535;
        const int n = j >> 8, k = j & 255;
        const float* dtW = dir ? dtbW : dtfW;      // (256,16)
        const float* Qd = Q + dir * 4096;
        float s = 0.f;
#pragma unroll
        for (int r = 0; r < 16; ++r) s = fmaf(dtW[n * 16 + r], Qd[r * 256 + k], s);
        wsH[idx] = f2b(s);
    } else if (idx >= 409600 && idx < 475136) {
        wsH[idx] = f2b(outW[idx - 409600]);
    }
}

// ---------------- merged row LayerNorm for both inputs, bf16 out ----------------
// grid 16384: blocks [0,8192) -> input0 -> x0h; [8192,16384) -> input1 -> x1h
__global__ __launch_bounds__(64) void ln_rows2(
    const float* __restrict__ in0, const float* __restrict__ in1,
    const float* __restrict__ g0, const float* __restrict__ b0,
    const float* __restrict__ g1, const float* __restrict__ b1,
    u16* __restrict__ x0h, u16* __restrict__ x1h)
{
    const int which = blockIdx.x >> 13;
    const int row = blockIdx.x & 8191;
    const float* in = which ? in1 : in0;
    const float* g  = which ? g1 : g0;
    const float* bb = which ? b1 : b0;
    u16* outh = which ? x1h : x0h;
    const int t = threadIdx.x;
    const size_t off = (size_t)row * 256 + t * 4;
    float4 v = ld4(&in[off]);
    float s = v.x + v.y + v.z + v.w;
    float s2 = v.x * v.x + v.y * v.y + v.z * v.z + v.w * v.w;
#pragma unroll
    for (int dl = 1; dl < 64; dl <<= 1) { s += __shfl_xor(s, dl); s2 += __shfl_xor(s2, dl); }
    const float m = s * (1.f / 256.f);
    const float var = s2 * (1.f / 256.f) - m * m;
    const float rstd = rsqrtf(var + 1e-5f);
    const float4 gv = ld4(&g[t * 4]);
    const float4 bv = ld4(&bb[t * 4]);
    ushort4 h;
    h.x = f2b((v.x - m) * rstd * gv.x + bv.x);
    h.y = f2b((v.y - m) * rstd * gv.y + bv.y);
    h.z = f2b((v.z - m) * rstd * gv.z + bv.z);
    h.w = f2b((v.w - m) * rstd * gv.w + bv.w);
    *reinterpret_cast<ushort4*>(&outh[off]) = h;
}

// ---------------- fused MFMA GEMM with LDS-staged B panel ----------------
// grid (64 m-tiles of 128, 21 by). block 256 = 4 waves; tile 128(M)x64(N);
// by: 0-3 x | 4-7 z | 8-11 w(sigmoid,K=512 two halves) | 12-15 dtf | 16-19 dtb | 20 bc
// B panel: 64 rows x 32 chunks(8 u16) in LDS, XOR-swizzled (byte ^= (row&7)<<4).
// x/z outputs: bf16 transposed [b][d][l]. dt/bc: fp32 chunk-transposed
// scan-order layout [row][s4][tt][j] (bwd pre-reversed).
__global__ __launch_bounds__(256) void gemm_mfma(
    const u16* __restrict__ x0h, const u16* __restrict__ x1h, const u16* __restrict__ wsH,
    const float* __restrict__ cwb, const float* __restrict__ dtfb, const float* __restrict__ dtbb,
    u16* __restrict__ xTh, u16* __restrict__ zTh, float* __restrict__ wbuf,
    float* __restrict__ dtfT, float* __restrict__ dtbT,
    float* __restrict__ bcfT, float* __restrict__ bcbT)
{
    __shared__ __align__(16) u16 Blds[64 * 256];   // 32 KB
    const int t = threadIdx.x;
    const int lane = t & 63;
    const int wid = t >> 6;
    const int col = lane & 15;
    const int kq = lane >> 4;
    const int m0 = blockIdx.x * 128;
    const int by = blockIdx.y;

    int seg, nbase, ldk, nhalf; const u16* W;
    if (by < 4)       { seg = 0; W = wsH + (size_t)(by * 64) * 256;                 ldk = 256; nhalf = 1; nbase = by * 64; }
    else if (by < 8)  { seg = 1; W = wsH + (size_t)(by * 64) * 256;                 ldk = 256; nhalf = 1; nbase = (by - 4) * 64; }
    else if (by < 12) { seg = 2; W = wsH + 131072 + (size_t)((by - 8) * 64) * 512;  ldk = 512; nhalf = 2; nbase = (by - 8) * 64; }
    else if (by < 16) { seg = 3; W = wsH + 262144 + (size_t)((by - 12) * 64) * 256; ldk = 256; nhalf = 1; nbase = (by - 12) * 64; }
    else if (by < 20) { seg = 4; W = wsH + 327680 + (size_t)((by - 16) * 64) * 256; ldk = 256; nhalf = 1; nbase = (by - 16) * 64; }
    else              { seg = 5; W = wsH + 393216;                                  ldk = 256; nhalf = 1; nbase = 0; }

    const u16* A0 = (seg >= 3) ? x1h : x0h;
    const int arow = m0 + wid * 32 + col;

    f32x4 acc[2][4] = {};
    for (int half = 0; half < nhalf; ++half) {
        if (half) __syncthreads();
#pragma unroll
        for (int it = 0; it < 8; ++it) {
            const int c = it * 256 + t;
            const int row = c >> 5, kc = c & 31;
            const bf16x8 v = *reinterpret_cast<const bf16x8*>(W + (size_t)row * ldk + half * 256 + kc * 8);
            const unsigned byt = ((unsigned)(row * 512 + kc * 16)) ^ (((unsigned)row & 7u) << 4);
            *reinterpret_cast<bf16x8*>(reinterpret_cast<char*>(Blds) + byt) = v;
        }
        __syncthreads();
        const u16* Ap = (seg == 2 && half) ? x1h : A0;
        const u16* Abase = Ap + (size_t)arow * 256;
        for (int k0 = 0; k0 < 256; k0 += 32) {
            const int kk = k0 + kq * 8;
            const bf16x8 a0 = *reinterpret_cast<const bf16x8*>(Abase + kk);
            const bf16x8 a1 = *reinterpret_cast<const bf16x8*>(Abase + 16 * 256 + kk);
#pragma unroll
            for (int nf = 0; nf < 4; ++nf) {
                const int n = nf * 16 + col;
                const unsigned byt = ((unsigned)(n * 512 + k0 * 2 + kq * 16)) ^ (((unsigned)n & 7u) << 4);
                const bf16x8 bfr = *reinterpret_cast<const bf16x8*>(reinterpret_cast<const char*>(Blds) + byt);
                acc[0][nf] = __builtin_amdgcn_mfma_f32_16x16x32_bf16(a0, bfr, acc[0][nf], 0, 0, 0);
                acc[1][nf] = __builtin_amdgcn_mfma_f32_16x16x32_bf16(a1, bfr, acc[1][nf], 0, 0, 0);
            }
        }
    }

    const int bb2 = m0 >> 12;
    const int l0 = m0 & (LL - 1);

    if (seg == 0 || seg == 1) {
        u16* dst = (seg == 0) ? xTh : zTh;
#pragma unroll
        for (int rg = 0; rg < 2; ++rg) {
            const int mrow = wid * 32 + rg * 16 + kq * 4;
#pragma unroll
            for (int nf = 0; nf < 4; ++nf) {
                const int d = nbase + nf * 16 + col;
                ushort4 h;
                h.x = f2b(acc[rg][nf][0]); h.y = f2b(acc[rg][nf][1]);
                h.z = f2b(acc[rg][nf][2]); h.w = f2b(acc[rg][nf][3]);
                *reinterpret_cast<ushort4*>(&dst[((size_t)bb2 * DD + d) * LL + l0 + mrow]) = h;
            }
        }
    } else if (seg == 2) {
#pragma unroll
        for (int rg = 0; rg < 2; ++rg) {
            const int mrow = wid * 32 + rg * 16 + kq * 4;
#pragma unroll
            for (int nf = 0; nf < 4; ++nf) {
                const int n = nbase + nf * 16 + col;
                const float bv = cwb[n];
#pragma unroll
                for (int r = 0; r < 4; ++r)
                    wbuf[(size_t)(m0 + mrow + r) * 256 + n] = 1.f / (1.f + expf(-(acc[rg][nf][r] + bv)));
            }
        }
    } else if (seg == 3 || seg == 4) {
        const float* bias = (seg == 3) ? dtfb : dtbb;
        float* dst = (seg == 3) ? dtfT : dtbT;
#pragma unroll
        for (int rg = 0; rg < 2; ++rg) {
            const int tt = (l0 >> 4) + wid * 2 + rg;
#pragma unroll
            for (int nf = 0; nf < 4; ++nf) {
                const int d = nbase + nf * 16 + col;
                const float bv = bias[d];
                f32x4 o;
#pragma unroll
                for (int r = 0; r < 4; ++r) o[r] = softplusf(acc[rg][nf][r] + bv);
                const size_t rowb = ((size_t)bb2 * DD + d) * LL;
                if (seg == 3) {
                    *reinterpret_cast<f32x4*>(&dst[rowb + kq * 1024 + tt * 4]) = o;
                } else {
                    f32x4 orv = { o[3], o[2], o[1], o[0] };
                    *reinterpret_cast<f32x4*>(&dst[rowb + (3 - kq) * 1024 + (255 - tt) * 4]) = orv;
                }
            }
        }
    } else {
#pragma unroll
        for (int rg = 0; rg < 2; ++rg) {
            const int tt = (l0 >> 4) + wid * 2 + rg;
#pragma unroll
            for (int nf = 0; nf < 4; ++nf) {
                const int n = nf * 16 + col;
                const int comp = n & 31;
                if (n < 32) {
                    const size_t rowb = ((size_t)bb2 * 32 + comp) * LL;
                    *reinterpret_cast<f32x4*>(&bcfT[rowb + kq * 1024 + tt * 4]) = acc[rg][nf];
                } else {
                    const f32x4 a = acc[rg][nf];
                    f32x4 arv = { a[3], a[2], a[1], a[0] };
                    const size_t rowb = ((size_t)bb2 * 32 + comp) * LL;
                    *reinterpret_cast<f32x4*>(&bcbT[rowb + (3 - kq) * 1024 + (255 - tt) * 4]) = arv;
                }
            }
        }
    }
}

// ---------------- out-proj MFMA GEMM (row-major out), LDS-staged B ----------------
__global__ __launch_bounds__(256) void gemm_out_mfma(
    const u16* __restrict__ ynh, const u16* __restrict__ wsH, float* __restrict__ out)
{
    __shared__ __align__(16) u16 Blds[64 * 256];
    const int t = threadIdx.x;
    const int lane = t & 63;
    const int wid = t >> 6;
    const int col = lane & 15;
    const int kq = lane >> 4;
    const int m0 = blockIdx.x * 128;
    const int n0 = blockIdx.y * 64;
    const u16* W = wsH + 409600 + (size_t)n0 * 256;
    const int arow = m0 + wid * 32 + col;

#pragma unroll
    for (int it = 0; it < 8; ++it) {
        const int c = it * 256 + t;
        const int row = c >> 5, kc = c & 31;
        const bf16x8 v = *reinterpret_cast<const bf16x8*>(W + (size_t)row * 256 + kc * 8);
        const unsigned byt = ((unsigned)(row * 512 + kc * 16)) ^ (((unsigned)row & 7u) << 4);
        *reinterpret_cast<bf16x8*>(reinterpret_cast<char*>(Blds) + byt) = v;
    }
    __syncthreads();

    f32x4 acc[2][4] = {};
    const u16* Abase = ynh + (size_t)arow * 256;
    for (int k0 = 0; k0 < 256; k0 += 32) {
        const int kk = k0 + kq * 8;
        const bf16x8 a0 = *reinterpret_cast<const bf16x8*>(Abase + kk);
        const bf16x8 a1 = *reinterpret_cast<const bf16x8*>(Abase + 16 * 256 + kk);
#pragma unroll
        for (int nf = 0; nf < 4; ++nf) {
            const int n = nf * 16 + col;
            const unsigned byt = ((unsigned)(n * 512 + k0 * 2 + kq * 16)) ^ (((unsigned)n & 7u) << 4);
            const bf16x8 bfr = *reinterpret_cast<const bf16x8*>(reinterpret_cast<const char*>(Blds) + byt);
            acc[0][nf] = __builtin_amdgcn_mfma_f32_16x16x32_bf16(a0, bfr, acc[0][nf], 0, 0, 0);
            acc[1][nf] = __builtin_amdgcn_mfma_f32_16x16x32_bf16(a1, bfr, acc[1][nf], 0, 0, 0);
        }
    }
#pragma unroll
    for (int rg = 0; rg < 2; ++rg) {
        const int mrow = wid * 32 + rg * 16 + kq * 4;
#pragma unroll
        for (int nf = 0; nf < 4; ++nf) {
            const int n = n0 + nf * 16 + col;
#pragma unroll
            for (int r = 0; r < 4; ++r)
                out[(size_t)(m0 + mrow + r) * 256 + n] = acc[rg][nf][r];
        }
    }
}

// ---------------- selective scan (round-10 structure, bf16 x/z/y) ----------------
// grid (256 d, 2 b, 2 dir), block 256. Thread j owns scan positions p=[16j,16j+16).
// dt/B/C arrive in scan-ordered chunk-transposed fp32 layout -> coalesced,
// no reversal. x/z read as bf16; y written as bf16. Per state n: scalar
// cross-thread prefix (P,S). n-loop MUST NOT unroll (spill lesson, rounds 2-4).
__global__ __launch_bounds__(256) void scan_kernel(
    const u16* __restrict__ xTh, const u16* __restrict__ zTh,
    const float* __restrict__ dtfT, const float* __restrict__ dtbT,
    const float* __restrict__ bcfT, const float* __restrict__ bcbT,
    const float* __restrict__ cfW, const float* __restrict__ cfB,
    const float* __restrict__ cbW, const float* __restrict__ cbB,
    const float* __restrict__ AlF, const float* __restrict__ AlB,
    const float* __restrict__ DF, const float* __restrict__ DB,
    u16* __restrict__ yFh, u16* __restrict__ yBh)
{
    const int d = blockIdx.x;
    const int b = blockIdx.y;
    const int dir = blockIdx.z;
    const int t = threadIdx.x;
    const int lane = t & 63;
    const int wv = t >> 6;
    const int fwd = (dir == 0);
    const float* dtT = fwd ? dtfT : dtbT;
    const float* bcT = fwd ? bcfT : bcbT;
    const float* cW  = fwd ? cfW  : cbW;
    const float* cBv = fwd ? cfB  : cbB;
    const float* Al  = fwd ? AlF  : AlB;
    const float* Dp  = fwd ? DF   : DB;
    u16* yout = fwd ? yFh : yBh;

    const int p0 = t * 16;
    const size_t xbase = ((size_t)b * DD + d) * LL;
    const int ls = LL - 16 - p0;
    const int off16 = fwd ? p0 : ls;

    const float Dd = Dp[d];
    const float c0 = cW[d * 4 + 0], c1 = cW[d * 4 + 1], c2 = cW[d * 4 + 2], c3 = cW[d * 4 + 3];
    const float cbias = cBv[d];

    // x window xq[i] = xseq(p0 - 3 + i)
    float xq[19];
    load16h(&xTh[xbase + off16], fwd, xq + 3);
    if (fwd) {
        xq[2] = (p0 >= 1) ? b2f(xTh[xbase + p0 - 1]) : 0.f;
        xq[1] = (p0 >= 2) ? b2f(xTh[xbase + p0 - 2]) : 0.f;
        xq[0] = (p0 >= 3) ? b2f(xTh[xbase + p0 - 3]) : 0.f;
    } else {
        xq[2] = (p0 >= 1) ? b2f(xTh[xbase + LL - p0]) : 0.f;
        xq[1] = (p0 >= 2) ? b2f(xTh[xbase + LL + 1 - p0]) : 0.f;
        xq[0] = (p0 >= 3) ? b2f(xTh[xbase + LL + 2 - p0]) : 0.f;
    }

    float dt[16];
    load16s(dtT + xbase, t, dt);

    float dtxs[16], yacc[16];
#pragma unroll
    for (int s = 0; s < 16; ++s) {
        float c = fmaf(xq[s], c0, fmaf(xq[s + 1], c1, fmaf(xq[s + 2], c2, fmaf(xq[s + 3], c3, cbias))));
        const float xv = c / (1.f + expf(-c));
        dtxs[s] = dt[s] * xv;
        yacc[s] = Dd * xv;
    }

    const float* bcb0 = bcT + (size_t)b * 32 * LL;

    __shared__ float wPs[2][4];
    __shared__ float wSs[2][4];

#pragma unroll 1
    for (int n = 0; n < 16; ++n) {
        const float a2 = -expf(Al[d * 16 + n]) * 1.4426950408889634f;
        float Bn[16], Cn[16];
        load16s(bcb0 + (size_t)n * LL, t, Bn);
        load16s(bcb0 + (size_t)(16 + n) * LL, t, Cn);   // used after scan -> latency hidden
        float pw[16], hl[16];
        float Pl = 1.f, Sl = 0.f;
#pragma unroll
        for (int s = 0; s < 16; ++s) {
            const float w = exp2f(dt[s] * a2);
            Sl = fmaf(w, Sl, dtxs[s] * Bn[s]);
            Pl *= w;
            pw[s] = Pl; hl[s] = Sl;
        }
        // wave-inclusive scan of (Pl,Sl)
#pragma unroll
        for (int dl = 1; dl < 64; dl <<= 1) {
            const float Pp = __shfl_up(Pl, dl);
            const float Sp = __shfl_up(Sl, dl);
            if (lane >= dl) { Sl = fmaf(Pl, Sp, Sl); Pl *= Pp; }
        }
        const int buf = n & 1;
        if (lane == 63) { wPs[buf][wv] = Pl; wSs[buf][wv] = Sl; }
        __syncthreads();
        float WSv = 0.f;
#pragma unroll
        for (int w2 = 0; w2 < 3; ++w2)
            if (w2 < wv) WSv = fmaf(wPs[buf][w2], WSv, wSs[buf][w2]);
        const float Pex = __shfl_up(Pl, 1);
        const float Sex = __shfl_up(Sl, 1);
        const float hin = lane ? fmaf(Pex, WSv, Sex) : WSv;
#pragma unroll
        for (int s = 0; s < 16; ++s)
            yacc[s] = fmaf(fmaf(pw[s], hin, hl[s]), Cn[s], yacc[s]);
    }

    float zq[16];
    load16h(&zTh[xbase + off16], fwd, zq);
    float yv[16];
#pragma unroll
    for (int s = 0; s < 16; ++s) {
        const float zz = zq[s];
        yv[s] = yacc[s] * zz / (1.f + expf(-zz));
    }

    // pack 16 bf16 into 2 x uint4 stores
#pragma unroll
    for (int g = 0; g < 2; ++g) {
        uint4 U;
        unsigned* up = reinterpret_cast<unsigned*>(&U);
        if (fwd) {
#pragma unroll
            for (int j = 0; j < 4; ++j)
                up[j] = (unsigned)f2b(yv[8 * g + 2 * j]) | ((unsigned)f2b(yv[8 * g + 2 * j + 1]) << 16);
            *reinterpret_cast<uint4*>(&yout[xbase + p0 + 8 * g]) = U;
        } else {
            // position ls+8g+i holds yv[15-8g-i]
#pragma unroll
            for (int j = 0; j < 4; ++j)
                up[j] = (unsigned)f2b(yv[15 - 8 * g - 2 * j]) | ((unsigned)f2b(yv[15 - 8 * g - 2 * j - 1]) << 16);
            *reinterpret_cast<uint4*>(&yout[xbase + ls + 8 * g]) = U;
        }
    }
}

// ---------------- (yf+yb)/2 + transpose + outnorm LN fused, bf16 in/out ----------------
// grid (128 l-tiles of 32, 2 b), block 256
__global__ __launch_bounds__(256) void comb_ln(
    const u16* __restrict__ yFh, const u16* __restrict__ yBh,
    const float* __restrict__ g, const float* __restrict__ bb,
    u16* __restrict__ out)
{
    __shared__ float tile[256][33];
    __shared__ float rs[8][32];
    __shared__ float rs2[8][32];
    const int b = blockIdx.y;
    const int l0 = blockIdx.x * 32;
    const int t = threadIdx.x;
    {
        const size_t base = ((size_t)b * DD + t) * LL + l0;
#pragma unroll
        for (int k = 0; k < 4; ++k) {
            const uint4 fa = *reinterpret_cast<const uint4*>(&yFh[base + 8 * k]);
            const uint4 ba = *reinterpret_cast<const uint4*>(&yBh[base + 8 * k]);
            const unsigned* fu = reinterpret_cast<const unsigned*>(&fa);
            const unsigned* bu = reinterpret_cast<const unsigned*>(&ba);
#pragma unroll
            for (int j = 0; j < 4; ++j) {
                tile[t][8 * k + 2 * j]     = (b2f(fu[j] & 0xffffu) + b2f(bu[j] & 0xffffu)) * 0.5f;
                tile[t][8 * k + 2 * j + 1] = (b2f(fu[j] >> 16) + b2f(bu[j] >> 16)) * 0.5f;
            }
        }
    }
    __syncthreads();
    const int l = t & 31;
    const int grp = t >> 5;
    float s = 0.f, s2 = 0.f;
#pragma unroll
    for (int i = 0; i < 32; ++i) {
        const float v = tile[grp * 32 + i][l];
        s += v; s2 = fmaf(v, v, s2);
    }
    rs[grp][l] = s; rs2[grp][l] = s2;
    __syncthreads();
    float st = 0.f, st2 = 0.f;
#pragma unroll
    for (int gq = 0; gq < 8; ++gq) { st += rs[gq][l]; st2 += rs2[gq][l]; }
    const float m = st * (1.f / 256.f);
    const float var = st2 * (1.f / 256.f) - m * m;
    const float rstd = rsqrtf(var + 1e-5f);
    const size_t obase = ((size_t)b * LL + l0 + l) * 256 + grp * 32;
#pragma unroll
    for (int k = 0; k < 8; ++k) {
        const float4 gv = ld4(&g[grp * 32 + 4 * k]);
        const float4 bv2 = ld4(&bb[grp * 32 + 4 * k]);
        ushort4 h;
        h.x = f2b((tile[grp * 32 + 4 * k + 0][l] - m) * rstd * gv.x + bv2.x);
        h.y = f2b((tile[grp * 32 + 4 * k + 1][l] - m) * rstd * gv.y + bv2.y);
        h.z = f2b((tile[grp * 32 + 4 * k + 2][l] - m) * rstd * gv.z + bv2.z);
        h.w = f2b((tile[grp * 32 + 4 * k + 3][l] - m) * rstd * gv.w + bv2.w);
        *reinterpret_cast<ushort4*>(&out[obase + 4 * k]) = h;
    }
}

// ---------------- post-LN + gated blend + skip (LN(in0) recomputed inline) ----------------
__global__ __launch_bounds__(64) void final_kernel(
    const float* __restrict__ o, const float* __restrict__ w,
    const float* __restrict__ in0,
    const float* __restrict__ n0g, const float* __restrict__ n0b,
    const float* __restrict__ pg, const float* __restrict__ pb,
    float* __restrict__ outp)
{
    const int row = blockIdx.x;
    const int t = threadIdx.x;
    const size_t off = (size_t)row * 256 + t * 4;
    float4 v = ld4(&o[off]);
    float4 iv = ld4(&in0[off]);
    float s = v.x + v.y + v.z + v.w;
    float s2 = v.x * v.x + v.y * v.y + v.z * v.z + v.w * v.w;
    float si = iv.x + iv.y + iv.z + iv.w;
    float si2 = iv.x * iv.x + iv.y * iv.y + iv.z * iv.z + iv.w * iv.w;
#pragma unroll
    for (int dl = 1; dl < 64; dl <<= 1) {
        s += __shfl_xor(s, dl); s2 += __shfl_xor(s2, dl);
        si += __shfl_xor(si, dl); si2 += __shfl_xor(si2, dl);
    }
    const float m = s * (1.f / 256.f);
    const float rstd = rsqrtf(s2 * (1.f / 256.f) - m * m + 1e-5f);
    const float mi = si * (1.f / 256.f);
    const float rstdi = rsqrtf(si2 * (1.f / 256.f) - mi * mi + 1e-5f);
    const float4 gv = ld4(&pg[t * 4]);
    const float4 bv = ld4(&pb[t * 4]);
    const float4 g0 = ld4(&n0g[t * 4]);
    const float4 b0 = ld4(&n0b[t * 4]);
    const float4 wv = ld4(&w[off]);
    float4 r;
    const float x0x = (iv.x - mi) * rstdi * g0.x + b0.x;
    const float x0y = (iv.y - mi) * rstdi * g0.y + b0.y;
    const float x0z = (iv.z - mi) * rstdi * g0.z + b0.z;
    const float x0w = (iv.w - mi) * rstdi * g0.w + b0.w;
    r.x = ((v.x - m) * rstd * gv.x + bv.x) * wv.x + x0x * (1.f - wv.x) + iv.x;
    r.y = ((v.y - m) * rstd * gv.y + bv.y) * wv.y + x0y * (1.f - wv.y) + iv.y;
    r.z = ((v.z - m) * rstd * gv.z + bv.z) * wv.z + x0z * (1.f - wv.z) + iv.z;
    r.w = ((v.w - m) * rstd * gv.w + bv.w) * wv.w + x0w * (1.f - wv.w) + iv.w;
    st4(&outp[off], r);
}

extern "C" void kernel_launch(void* const* d_in, const int* in_sizes, int n_in,
                              void* d_out, int out_size, void* d_ws, size_t ws_size,
                              hipStream_t stream) {
    (void)in_sizes; (void)n_in; (void)out_size; (void)ws_size;
    const float* in0      = (const float*)d_in[0];
    const float* in1      = (const float*)d_in[1];
    const float* norm0_g  = (const float*)d_in[2];
    const float* norm0_b  = (const float*)d_in[3];
    const float* norm1_g  = (const float*)d_in[4];
    const float* norm1_b  = (const float*)d_in[5];
    const float* cw_W     = (const float*)d_in[6];
    const float* cw_b     = (const float*)d_in[7];
    const float* in_proj_W    = (const float*)d_in[8];
    const float* extra_proj_W = (const float*)d_in[9];
    const float* convf_W  = (const float*)d_in[10];
    const float* convf_b  = (const float*)d_in[11];
    const float* xprojf_W = (const float*)d_in[12];
    const float* dtf_W    = (const float*)d_in[13];
    const float* dtf_b    = (const float*)d_in[14];
    const float* A_log_f  = (const float*)d_in[15];
    const float* D_f      = (const float*)d_in[16];
    const float* convb_W  = (const float*)d_in[17];
    const float* convb_b  = (const float*)d_in[18];
    const float* xprojb_W = (const float*)d_in[19];
    const float* dtb_W    = (const float*)d_in[20];
    const float* dtb_b    = (const float*)d_in[21];
    const float* A_log_b  = (const float*)d_in[22];
    const float* D_b      = (const float*)d_in[23];
    const float* outnorm_g = (const float*)d_in[24];
    const float* outnorm_b = (const float*)d_in[25];
    const float* out_proj_W = (const float*)d_in[26];
    const float* post_g   = (const float*)d_in[27];
    const float* post_b   = (const float*)d_in[28];

    float* ws = (float*)d_ws;
    float* xzr   = ws;                  // u16 region: xTh (NEL u16) + zTh (NEL u16)
    float* dtfT  = ws + NEL;            // fp32, dead after scan -> ynorm (bf16)
    float* dtbT  = ws + 2 * NEL;        // fp32, dead after scan -> obuf
    float* wbuf  = ws + 3 * NEL;        // fp32 gate
    float* yFr   = ws + 4 * NEL;        // u16 region: x0h/x1h before scan; yFh after
    float* yBr   = ws + 5 * NEL;        // u16 region: yBh
    float* bcfT  = ws + 6 * NEL;                     // 262144 floats
    float* bcbT  = bcfT + (size_t)BB * 32 * LL;      // 262144 floats
    u16*   wsH   = (u16*)(bcbT + (size_t)BB * 32 * LL);  // 475136 u16
    float* Qtmp  = (float*)(wsH + 475136);               // 8192 floats

    u16* xTh = (u16*)xzr;
    u16* zTh = xTh + NEL;
    u16* x0h = (u16*)yFr;               // NEL u16
    u16* x1h = x0h + NEL;               // NEL u16
    u16* yFh = (u16*)yFr;               // scan fwd out (overwrites x0h; x dead then)
    u16* yBh = (u16*)yBr;
    u16* ynormh = (u16*)dtfT;
    float* obuf = dtbT;

    prep_q<<<96, 256, 0, stream>>>(xprojf_W, xprojb_W, extra_proj_W, Qtmp, wsH);
    prep_w<<<1856, 256, 0, stream>>>(in_proj_W, cw_W, out_proj_W, dtf_W, dtb_W, Qtmp, wsH);
    ln_rows2<<<2 * BB * LL, 64, 0, stream>>>(in0, in1, norm0_g, norm0_b, norm1_g, norm1_b,
                                             x0h, x1h);
    gemm_mfma<<<dim3(64, 21, 1), 256, 0, stream>>>(x0h, x1h, wsH, cw_b, dtf_b, dtb_b,
                                                   xTh, zTh, wbuf, dtfT, dtbT, bcfT, bcbT);
    scan_kernel<<<dim3(256, 2, 2), 256, 0, stream>>>(xTh, zTh, dtfT, dtbT, bcfT, bcbT,
                                                     convf_W, convf_b, convb_W, convb_b,
                                                     A_log_f, A_log_b, D_f, D_b,
                                                     yFh, yBh);
    comb_ln<<<dim3(128, 2, 1), 256, 0, stream>>>(yFh, yBh, outnorm_g, outnorm_b, ynormh);
    gemm_out_mfma<<<dim3(64, 4, 1), 256, 0, stream>>>(ynormh, wsH, obuf);
    final_kernel<<<BB * LL, 64, 0, stream>>>(obuf, wbuf, in0, norm0_g, norm0_b,
                                             post_g, post_b, (float*)d_out);
}